// Round 9
// baseline (195.016 us; speedup 1.0000x reference)
//
#include <hip/hip_runtime.h>
#include <hip/hip_bf16.h>
#include <stdint.h>

#define NHEADS 16
#define DKH    64
#define BB     2
#define SS     2048
#define DM     1024
#define MROWS  (BB * SS)   // 4096

typedef __attribute__((ext_vector_type(8))) short bf8_t;   // 8 bf16 in 4 VGPRs
typedef __attribute__((ext_vector_type(4))) float f4_t;    // MFMA accum
typedef unsigned short u16;
typedef uint32_t u32;

#define SCL 0.180336880f   // (1/8) * log2(e), folded into Q at gemm0 epilogue

__device__ __forceinline__ u16 f2bf(float f) {
    union { float f; u32 u; } v; v.f = f;
    return (u16)((v.u + 0x7fffu + ((v.u >> 16) & 1u)) >> 16);  // RNE
}

__device__ __forceinline__ u32 cvt_pk_bf16(float lo, float hi) {
    u32 r;
    asm("v_cvt_pk_bf16_f32 %0, %1, %2" : "=v"(r) : "v"(lo), "v"(hi));
    return r;
}

__device__ __forceinline__ float fexp2(float x) {
#if __has_builtin(__builtin_amdgcn_exp2f)
    return __builtin_amdgcn_exp2f(x);
#else
    return __expf(x * 0.69314718056f);
#endif
}

__device__ __forceinline__ void async_copy16(void* lds, const void* g) {
    __builtin_amdgcn_global_load_lds(
        (__attribute__((address_space(1))) void*)(void*)g,
        (__attribute__((address_space(3))) void*)lds, 16, 0, 0);
}

#define MFMA32(a, b, c) __builtin_amdgcn_mfma_f32_16x16x32_bf16(a, b, c, 0, 0, 0)

// ---------------- prep: x->bf16, Wqkv^T, Wo^T in one launch ----------------
__global__ __launch_bounds__(256) void k_prep(
    const float* __restrict__ x, const float* __restrict__ Wqkv,
    const float* __restrict__ Wo,
    u16* __restrict__ xb, u16* __restrict__ Wqkt, u16* __restrict__ Wot)
{
    __shared__ float tile[32][33];
    const int blk = blockIdx.x;
    const int tx = threadIdx.x & 31, ty = threadIdx.x >> 5;
    if (blk < 3072) {          // Wqkv (DM x 3DM) -> Wqkt (3DM x DM)
        const int n0 = (blk % 96) * 32, k0 = (blk / 96) * 32;
        #pragma unroll
        for (int r = ty; r < 32; r += 8)
            tile[r][tx] = Wqkv[(size_t)(k0 + r) * (3 * DM) + n0 + tx];
        __syncthreads();
        #pragma unroll
        for (int r = ty; r < 32; r += 8)
            Wqkt[(size_t)(n0 + r) * DM + k0 + tx] = f2bf(tile[tx][r]);
    } else if (blk < 4096) {   // Wo (DM x DM) -> Wot (DM x DM)
        const int b2 = blk - 3072;
        const int n0 = (b2 % 32) * 32, k0 = (b2 / 32) * 32;
        #pragma unroll
        for (int r = ty; r < 32; r += 8)
            tile[r][tx] = Wo[(size_t)(k0 + r) * DM + n0 + tx];
        __syncthreads();
        #pragma unroll
        for (int r = ty; r < 32; r += 8)
            Wot[(size_t)(n0 + r) * DM + k0 + tx] = f2bf(tile[tx][r]);
    } else {                   // x f32 -> bf16, 512 blocks grid-stride
        const int b2 = blk - 4096;
        const int n4 = (MROWS * DM) / 4;
        for (int i = b2 * 256 + threadIdx.x; i < n4; i += 512 * 256) {
            float4 v = ((const float4*)x)[i];
            ushort4 o;
            o.x = f2bf(v.x); o.y = f2bf(v.y); o.z = f2bf(v.z); o.w = f2bf(v.w);
            ((ushort4*)xb)[i] = o;
        }
    }
}

// ---------------- V[b,h,s,dk] -> Vt[b,h,dk,s] ----------------
__global__ __launch_bounds__(256) void k_vt(const u16* __restrict__ V, u16* __restrict__ Vt) {
    __shared__ u16 t[64][72];
    const int bh = blockIdx.y;
    const int s0 = blockIdx.x * 64;
    const u16* Vb = V + (size_t)bh * SS * DKH;
    u16* Tb = Vt + (size_t)bh * DKH * SS;
    const int tid = threadIdx.x;
    #pragma unroll
    for (int it = 0; it < 2; ++it) {
        const int c = tid + it * 256;
        const int r = c >> 3, sl = c & 7;
        *(uint4*)&t[r][sl * 8] = *(const uint4*)(Vb + (size_t)(s0 + r) * DKH + sl * 8);
    }
    __syncthreads();
    #pragma unroll
    for (int it = 0; it < 2; ++it) {
        const int c = tid + it * 256;
        const int d = c >> 3, sl = c & 7;
        uint4 o;
        o.x = t[sl * 8 + 0][d] | ((u32)t[sl * 8 + 1][d] << 16);
        o.y = t[sl * 8 + 2][d] | ((u32)t[sl * 8 + 3][d] << 16);
        o.z = t[sl * 8 + 4][d] | ((u32)t[sl * 8 + 5][d] << 16);
        o.w = t[sl * 8 + 6][d] | ((u32)t[sl * 8 + 7][d] << 16);
        *(uint4*)(Tb + (size_t)d * SS + s0 + sl * 8) = o;
    }
}

// ---------------- bf16 GEMM, double-buffered prefetch ----------------
template<int MODE, int BMT, int BNT>
__global__ __launch_bounds__(256) void k_gemm(
    const u16* __restrict__ A, const u16* __restrict__ Bt,
    const float* __restrict__ bias,
    u16* __restrict__ q_out, u16* __restrict__ k_out, u16* __restrict__ v_out,
    float* __restrict__ f_out,
    int N, int K)
{
    constexpr int MF = BMT / 32, NF = BNT / 32;
    __shared__ u16 As[2][BMT * 32];
    __shared__ u16 Bs[2][BNT * 32];
    const int m0 = blockIdx.y * BMT, n0 = blockIdx.x * BNT;
    const int tid = threadIdx.x;
    const int w = tid >> 6, l = tid & 63;
    const int lr = l >> 2, lc = (l & 3) * 8;
    const int fr = l & 15, fk = (l >> 4) * 8;
    const int wm = (w >> 1) * (BMT / 2), wn = (w & 1) * (BNT / 2);
    f4_t acc[MF][NF] = {};

    auto stage = [&](int kt, int buf) {
        #pragma unroll
        for (int cc = 0; cc < BMT / 64; ++cc) {
            const int c = w + cc * 4;
            async_copy16(&As[buf][c * 512], A + (size_t)(m0 + c * 16 + lr) * K + kt + lc);
        }
        #pragma unroll
        for (int cc = 0; cc < BNT / 64; ++cc) {
            const int c = w + cc * 4;
            async_copy16(&Bs[buf][c * 512], Bt + (size_t)(n0 + c * 16 + lr) * K + kt + lc);
        }
    };

    stage(0, 0);
    __syncthreads();
    int cur = 0;
    for (int kt = 0; kt < K; kt += 32) {
        if (kt + 32 < K) stage(kt + 32, cur ^ 1);
        bf8_t af[MF], bfr[NF];
        #pragma unroll
        for (int mf = 0; mf < MF; ++mf)
            af[mf] = *(const bf8_t*)&As[cur][(wm + mf * 16 + fr) * 32 + fk];
        #pragma unroll
        for (int nf = 0; nf < NF; ++nf)
            bfr[nf] = *(const bf8_t*)&Bs[cur][(wn + nf * 16 + fr) * 32 + fk];
        #pragma unroll
        for (int mf = 0; mf < MF; ++mf)
            #pragma unroll
            for (int nf = 0; nf < NF; ++nf)
                acc[mf][nf] = MFMA32(af[mf], bfr[nf], acc[mf][nf]);
        __syncthreads();
        cur ^= 1;
    }

    #pragma unroll
    for (int mf = 0; mf < MF; ++mf)
      #pragma unroll
      for (int nf = 0; nf < NF; ++nf)
        #pragma unroll
        for (int j = 0; j < 4; ++j) {
            const int m = m0 + wm + mf * 16 + (l >> 4) * 4 + j;
            const int n = n0 + wn + nf * 16 + (l & 15);
            float v = acc[mf][nf][j] + bias[n];
            if (MODE == 0) {
                const int h = n / 192, rem = n - h * 192;
                const int which = rem >> 6, dd = rem & 63;
                const int b = m >> 11, s = m & (SS - 1);
                const size_t idx = ((size_t)(b * NHEADS + h) * SS + s) * DKH + dd;
                if (which == 0) v *= SCL;   // fold softmax scale + log2e into Q
                u16* dst = (which == 0) ? q_out : ((which == 1) ? k_out : v_out);
                dst[idx] = f2bf(v);
            } else {
                f_out[(size_t)m * N + n] = v;
            }
        }
}

// ---------------- flash attention ----------------
// Round-6 structure verbatim (per-mf QK + softmax), adapted for pre-scaled Q
// (sa is directly in log2 units: no x*=SCL, P = exp2(sa - mrow)).
// Block: 4 waves x 32 q-rows = 128 q rows. Grid (32 bh, SS/128). KVBLK=128.
// Double-buffered K/V (64KB LDS), stage(t+1) issued before compute(t).
__global__ __launch_bounds__(256, 2) void k_attn(
    const u16* __restrict__ Qg, const u16* __restrict__ Kg, const u16* __restrict__ Vtg,
    u16* __restrict__ ctx)
{
    __shared__ u16 Ks[2][128 * 64];    // [staged key][dk]
    __shared__ u16 Vs[2][64 * 128];    // [dk][physical key]
    const int bh = blockIdx.x;
    const int qt = blockIdx.y;
    const int tid = threadIdx.x, w = tid >> 6, l = tid & 63;
    const int fr = l & 15, fq = l >> 4;
    const int q0 = qt * 128 + w * 32;
    const u16* Qb = Qg  + (size_t)bh * SS * DKH;
    const u16* Kb = Kg  + (size_t)bh * SS * DKH;
    const u16* Vb = Vtg + (size_t)bh * DKH * SS;

    bf8_t qf[2][2];   // [mf][kh]  B-frag: col=qrow, k = kh*32 + fq*8 + e
    #pragma unroll
    for (int mf = 0; mf < 2; ++mf)
      #pragma unroll
      for (int kh = 0; kh < 2; ++kh)
        qf[mf][kh] = *(const bf8_t*)(Qb + (size_t)(q0 + mf * 16 + fr) * DKH + kh * 32 + fq * 8);

    float mrow[2] = {-__builtin_inff(), -__builtin_inff()};
    float lrow[2] = {0.f, 0.f};
    f4_t o[2][4] = {};                 // O[mf][qrow=fq*4+j][d=df*16+fr]

    auto stage = [&](int kv, int buf) {
        #pragma unroll
        for (int it = 0; it < 4; ++it) {
            const int c = tid + it * 256;
            const int cb = it * 256 + w * 64;          // wave-uniform chunk base
            const int rk = c >> 3;
            const int slk = (c & 7) ^ (rk & 7);
            const int sr = ((rk >> 2) & 3) * 32 + (rk >> 4) * 4 + (rk & 3);  // sigma
            async_copy16(&Ks[buf][cb * 8], Kb + (size_t)(kv + sr) * DKH + slk * 8);
            const int rv = c >> 4;
            const int slv = (c & 15) ^ (rv & 7);
            async_copy16(&Vs[buf][cb * 8], Vb + (size_t)rv * SS + kv + slv * 8);
        }
    };

    stage(0, 0);
    __syncthreads();
    int cur = 0;
    for (int kv = 0; kv < SS; kv += 128) {
        if (kv + 128 < SS) stage(kv + 128, cur ^ 1);

        u32 pk[2][16];  // [mf][nf*2+h]: physkeys fq*32+nf*4+{2h,2h+1}
        #pragma unroll
        for (int mf = 0; mf < 2; ++mf) {
            // S^T = K * Q^T : sa[nf][j] = S[physkey = fq*32+nf*4+j][qrow]
            f4_t sa[8] = {};
            #pragma unroll
            for (int nf = 0; nf < 8; ++nf)
              #pragma unroll
              for (int kh = 0; kh < 2; ++kh) {
                const int row = nf * 16 + fr;
                const int dsl = (kh * 4 + fq) ^ (fr & 7);
                const bf8_t kb = *(const bf8_t*)&Ks[cur][row * 64 + dsl * 8];
                sa[nf] = MFMA32(kb, qf[mf][kh], sa[nf]);
              }

            float x = sa[0][0];
            #pragma unroll
            for (int nf = 0; nf < 8; ++nf)
              #pragma unroll
              for (int j = 0; j < 4; ++j)
                x = fmaxf(x, sa[nf][j]);
            x = fmaxf(x, __shfl_xor(x, 16));
            x = fmaxf(x, __shfl_xor(x, 32));

            if (__any(x > mrow[mf] + 8.f)) {       // defer-max (T13)
                float mnew = fmaxf(mrow[mf], x);
                float sc = fexp2(mrow[mf] - mnew);
                lrow[mf] *= sc;
                mrow[mf] = mnew;
                float sc4[4];
                #pragma unroll
                for (int j = 0; j < 4; ++j) sc4[j] = __shfl(sc, fq * 4 + j);
                #pragma unroll
                for (int df = 0; df < 4; ++df)
                  #pragma unroll
                  for (int j = 0; j < 4; ++j)
                    o[mf][df][j] *= sc4[j];
            }

            float ps = 0.f;
            #pragma unroll
            for (int nf = 0; nf < 8; ++nf) {
                float p0 = fexp2(sa[nf][0] - mrow[mf]);
                float p1 = fexp2(sa[nf][1] - mrow[mf]);
                float p2 = fexp2(sa[nf][2] - mrow[mf]);
                float p3 = fexp2(sa[nf][3] - mrow[mf]);
                ps += (p0 + p1) + (p2 + p3);
                pk[mf][nf * 2 + 0] = cvt_pk_bf16(p0, p1);
                pk[mf][nf * 2 + 1] = cvt_pk_bf16(p2, p3);
            }
            ps += __shfl_xor(ps, 16);
            ps += __shfl_xor(ps, 32);
            lrow[mf] += ps;
        }

        // O += P V : pa[mf] = physkeys [fq*32+8t, +8); vv reused across mf
        #pragma unroll
        for (int t = 0; t < 4; ++t) {
            union { bf8_t v; u32 u[4]; } pa0, pa1;
            #pragma unroll
            for (int i = 0; i < 4; ++i) { pa0.u[i] = pk[0][4 * t + i]; pa1.u[i] = pk[1][4 * t + i]; }
            const int sl = fq * 4 + t;
            #pragma unroll
            for (int df = 0; df < 4; ++df) {
                const int rv = df * 16 + fr;
                const int dsl = sl ^ (rv & 7);
                const bf8_t vv = *(const bf8_t*)&Vs[cur][rv * 128 + dsl * 8];
                o[0][df] = MFMA32(pa0.v, vv, o[0][df]);
                o[1][df] = MFMA32(pa1.v, vv, o[1][df]);
            }
        }
        __syncthreads();
        cur ^= 1;
    }

    const int b = bh >> 4, h = bh & 15;
    #pragma unroll
    for (int mf = 0; mf < 2; ++mf) {
        float ml[4];
        #pragma unroll
        for (int j = 0; j < 4; ++j) ml[j] = __shfl(lrow[mf], fq * 4 + j);
        #pragma unroll
        for (int df = 0; df < 4; ++df)
          #pragma unroll
          for (int j = 0; j < 4; ++j) {
            const int s = q0 + mf * 16 + fq * 4 + j;
            const int dd = df * 16 + fr;
            float v = o[mf][df][j] / ml[j];
            ctx[((size_t)(b * SS + s)) * DM + h * DKH + dd] = f2bf(v);
          }
    }
}

// ---------------- launcher ----------------
extern "C" void kernel_launch(void* const* d_in, const int* in_sizes, int n_in,
                              void* d_out, int out_size, void* d_ws, size_t ws_size,
                              hipStream_t stream)
{
    const float* x     = (const float*)d_in[0];
    const float* W_qkv = (const float*)d_in[1];
    const float* b_qkv = (const float*)d_in[2];
    const float* W_o   = (const float*)d_in[3];
    const float* b_o   = (const float*)d_in[4];
    float* out = (float*)d_out;

    char* ws = (char*)d_ws;
    u16* xb   = (u16*)(ws);                                   // 4096x1024  (8 MB)
    u16* Wqkt = (u16*)(ws + 8388608);                         // 3072x1024  (6 MB)
    u16* Wot  = (u16*)(ws + 8388608 + 6291456);               // 1024x1024  (2 MB)
    u16* Qg   = (u16*)(ws + 16777216);                        // 32x2048x64 (8 MB)
    u16* Kg   = Qg  + 4194304;
    u16* Vg   = Kg  + 4194304;                                // V linear
    u16* Vtg  = Vg  + 4194304;                                // V transposed
    u16* ctx  = xb;                                           // alias: xb dead after k_gemm<0>

    k_prep<<<4608, 256, 0, stream>>>(x, W_qkv, W_o, xb, Wqkt, Wot);
    k_gemm<0, 128, 128><<<dim3(3 * DM / 128, MROWS / 128), 256, 0, stream>>>(
        xb, Wqkt, b_qkv, Qg, Kg, Vg, nullptr, 3 * DM, DM);
    k_vt<<<dim3(SS / 64, BB * NHEADS), 256, 0, stream>>>(Vg, Vtg);
    k_attn<<<dim3(BB * NHEADS, SS / 128), 256, 0, stream>>>(Qg, Kg, Vtg, ctx);
    k_gemm<1, 128, 64><<<dim3(DM / 64, MROWS / 128), 256, 0, stream>>>(
        ctx, Wot, b_o, nullptr, nullptr, nullptr, out, DM, DM);
}

// Round 11
// 193.010 us; speedup vs baseline: 1.0104x; 1.0104x over previous
//
#include <hip/hip_runtime.h>
#include <hip/hip_bf16.h>
#include <stdint.h>

#define NHEADS 16
#define DKH    64
#define BB     2
#define SS     2048
#define DM     1024
#define MROWS  (BB * SS)   // 4096

typedef __attribute__((ext_vector_type(8))) short bf8_t;   // 8 bf16 in 4 VGPRs
typedef __attribute__((ext_vector_type(4))) float f4_t;    // MFMA accum
typedef unsigned short u16;
typedef uint32_t u32;

#define SCL 0.180336880f   // (1/8) * log2(e), folded into Q at gemm0 epilogue

__device__ __forceinline__ u16 f2bf(float f) {
    union { float f; u32 u; } v; v.f = f;
    return (u16)((v.u + 0x7fffu + ((v.u >> 16) & 1u)) >> 16);  // RNE
}

__device__ __forceinline__ u32 cvt_pk_bf16(float lo, float hi) {
    u32 r;
    asm("v_cvt_pk_bf16_f32 %0, %1, %2" : "=v"(r) : "v"(lo), "v"(hi));
    return r;
}

__device__ __forceinline__ float fexp2(float x) {
#if __has_builtin(__builtin_amdgcn_exp2f)
    return __builtin_amdgcn_exp2f(x);
#else
    return __expf(x * 0.69314718056f);
#endif
}

__device__ __forceinline__ void async_copy16(void* lds, const void* g) {
    __builtin_amdgcn_global_load_lds(
        (__attribute__((address_space(1))) void*)(void*)g,
        (__attribute__((address_space(3))) void*)lds, 16, 0, 0);
}

#define MFMA32(a, b, c) __builtin_amdgcn_mfma_f32_16x16x32_bf16(a, b, c, 0, 0, 0)

// ---------------- prep: x->bf16, Wqkv^T, Wo^T in one launch ----------------
__global__ __launch_bounds__(256) void k_prep(
    const float* __restrict__ x, const float* __restrict__ Wqkv,
    const float* __restrict__ Wo,
    u16* __restrict__ xb, u16* __restrict__ Wqkt, u16* __restrict__ Wot)
{
    __shared__ float tile[32][33];
    const int blk = blockIdx.x;
    const int tx = threadIdx.x & 31, ty = threadIdx.x >> 5;
    if (blk < 3072) {          // Wqkv (DM x 3DM) -> Wqkt (3DM x DM)
        const int n0 = (blk % 96) * 32, k0 = (blk / 96) * 32;
        #pragma unroll
        for (int r = ty; r < 32; r += 8)
            tile[r][tx] = Wqkv[(size_t)(k0 + r) * (3 * DM) + n0 + tx];
        __syncthreads();
        #pragma unroll
        for (int r = ty; r < 32; r += 8)
            Wqkt[(size_t)(n0 + r) * DM + k0 + tx] = f2bf(tile[tx][r]);
    } else if (blk < 4096) {   // Wo (DM x DM) -> Wot (DM x DM)
        const int b2 = blk - 3072;
        const int n0 = (b2 % 32) * 32, k0 = (b2 / 32) * 32;
        #pragma unroll
        for (int r = ty; r < 32; r += 8)
            tile[r][tx] = Wo[(size_t)(k0 + r) * DM + n0 + tx];
        __syncthreads();
        #pragma unroll
        for (int r = ty; r < 32; r += 8)
            Wot[(size_t)(n0 + r) * DM + k0 + tx] = f2bf(tile[tx][r]);
    } else {                   // x f32 -> bf16, 512 blocks grid-stride
        const int b2 = blk - 4096;
        const int n4 = (MROWS * DM) / 4;
        for (int i = b2 * 256 + threadIdx.x; i < n4; i += 512 * 256) {
            float4 v = ((const float4*)x)[i];
            ushort4 o;
            o.x = f2bf(v.x); o.y = f2bf(v.y); o.z = f2bf(v.z); o.w = f2bf(v.w);
            ((ushort4*)xb)[i] = o;
        }
    }
}

// ---------------- V[b,h,s,dk] -> Vt[b,h,dk,s] ----------------
__global__ __launch_bounds__(256) void k_vt(const u16* __restrict__ V, u16* __restrict__ Vt) {
    __shared__ u16 t[64][72];
    const int bh = blockIdx.y;
    const int s0 = blockIdx.x * 64;
    const u16* Vb = V + (size_t)bh * SS * DKH;
    u16* Tb = Vt + (size_t)bh * DKH * SS;
    const int tid = threadIdx.x;
    #pragma unroll
    for (int it = 0; it < 2; ++it) {
        const int c = tid + it * 256;
        const int r = c >> 3, sl = c & 7;
        *(uint4*)&t[r][sl * 8] = *(const uint4*)(Vb + (size_t)(s0 + r) * DKH + sl * 8);
    }
    __syncthreads();
    #pragma unroll
    for (int it = 0; it < 2; ++it) {
        const int c = tid + it * 256;
        const int d = c >> 3, sl = c & 7;
        uint4 o;
        o.x = t[sl * 8 + 0][d] | ((u32)t[sl * 8 + 1][d] << 16);
        o.y = t[sl * 8 + 2][d] | ((u32)t[sl * 8 + 3][d] << 16);
        o.z = t[sl * 8 + 4][d] | ((u32)t[sl * 8 + 5][d] << 16);
        o.w = t[sl * 8 + 6][d] | ((u32)t[sl * 8 + 7][d] << 16);
        *(uint4*)(Tb + (size_t)d * SS + s0 + sl * 8) = o;
    }
}

// ---------------- bf16 GEMM, double-buffered prefetch ----------------
template<int MODE, int BMT, int BNT>
__global__ __launch_bounds__(256) void k_gemm(
    const u16* __restrict__ A, const u16* __restrict__ Bt,
    const float* __restrict__ bias,
    u16* __restrict__ q_out, u16* __restrict__ k_out, u16* __restrict__ v_out,
    float* __restrict__ f_out,
    int N, int K)
{
    constexpr int MF = BMT / 32, NF = BNT / 32;
    __shared__ u16 As[2][BMT * 32];
    __shared__ u16 Bs[2][BNT * 32];
    const int m0 = blockIdx.y * BMT, n0 = blockIdx.x * BNT;
    const int tid = threadIdx.x;
    const int w = tid >> 6, l = tid & 63;
    const int lr = l >> 2, lc = (l & 3) * 8;
    const int fr = l & 15, fk = (l >> 4) * 8;
    const int wm = (w >> 1) * (BMT / 2), wn = (w & 1) * (BNT / 2);
    f4_t acc[MF][NF] = {};

    auto stage = [&](int kt, int buf) {
        #pragma unroll
        for (int cc = 0; cc < BMT / 64; ++cc) {
            const int c = w + cc * 4;
            async_copy16(&As[buf][c * 512], A + (size_t)(m0 + c * 16 + lr) * K + kt + lc);
        }
        #pragma unroll
        for (int cc = 0; cc < BNT / 64; ++cc) {
            const int c = w + cc * 4;
            async_copy16(&Bs[buf][c * 512], Bt + (size_t)(n0 + c * 16 + lr) * K + kt + lc);
        }
    };

    stage(0, 0);
    __syncthreads();
    int cur = 0;
    for (int kt = 0; kt < K; kt += 32) {
        if (kt + 32 < K) stage(kt + 32, cur ^ 1);
        bf8_t af[MF], bfr[NF];
        #pragma unroll
        for (int mf = 0; mf < MF; ++mf)
            af[mf] = *(const bf8_t*)&As[cur][(wm + mf * 16 + fr) * 32 + fk];
        #pragma unroll
        for (int nf = 0; nf < NF; ++nf)
            bfr[nf] = *(const bf8_t*)&Bs[cur][(wn + nf * 16 + fr) * 32 + fk];
        #pragma unroll
        for (int mf = 0; mf < MF; ++mf)
            #pragma unroll
            for (int nf = 0; nf < NF; ++nf)
                acc[mf][nf] = MFMA32(af[mf], bfr[nf], acc[mf][nf]);
        __syncthreads();
        cur ^= 1;
    }

    #pragma unroll
    for (int mf = 0; mf < MF; ++mf)
      #pragma unroll
      for (int nf = 0; nf < NF; ++nf)
        #pragma unroll
        for (int j = 0; j < 4; ++j) {
            const int m = m0 + wm + mf * 16 + (l >> 4) * 4 + j;
            const int n = n0 + wn + nf * 16 + (l & 15);
            float v = acc[mf][nf][j] + bias[n];
            if (MODE == 0) {
                const int h = n / 192, rem = n - h * 192;
                const int which = rem >> 6, dd = rem & 63;
                const int b = m >> 11, s = m & (SS - 1);
                const size_t idx = ((size_t)(b * NHEADS + h) * SS + s) * DKH + dd;
                if (which == 0) v *= SCL;   // fold softmax scale + log2e into Q
                u16* dst = (which == 0) ? q_out : ((which == 1) ? k_out : v_out);
                dst[idx] = f2bf(v);
            } else {
                f_out[(size_t)m * N + n] = v;
            }
        }
}

// ---------------- flash attention ----------------
// Per-mf QK + softmax (R6 structure), pre-scaled Q (sa in log2 units).
// Block: 4 waves x 32 q-rows = 128 q rows. Grid (32 bh, SS/128). KVBLK=128.
// Double-buffered K/V (64KB LDS), stage(t+1) issued before compute(t).
// T5: s_setprio(1) around MFMA clusters (attn-proven, m191).
__global__ __launch_bounds__(256, 2) void k_attn(
    const u16* __restrict__ Qg, const u16* __restrict__ Kg, const u16* __restrict__ Vtg,
    u16* __restrict__ ctx)
{
    __shared__ u16 Ks[2][128 * 64];    // [staged key][dk]
    __shared__ u16 Vs[2][64 * 128];    // [dk][physical key]
    const int bh = blockIdx.x;
    const int qt = blockIdx.y;
    const int tid = threadIdx.x, w = tid >> 6, l = tid & 63;
    const int fr = l & 15, fq = l >> 4;
    const int q0 = qt * 128 + w * 32;
    const u16* Qb = Qg  + (size_t)bh * SS * DKH;
    const u16* Kb = Kg  + (size_t)bh * SS * DKH;
    const u16* Vb = Vtg + (size_t)bh * DKH * SS;

    bf8_t qf[2][2];   // [mf][kh]  B-frag: col=qrow, k = kh*32 + fq*8 + e
    #pragma unroll
    for (int mf = 0; mf < 2; ++mf)
      #pragma unroll
      for (int kh = 0; kh < 2; ++kh)
        qf[mf][kh] = *(const bf8_t*)(Qb + (size_t)(q0 + mf * 16 + fr) * DKH + kh * 32 + fq * 8);

    float mrow[2] = {-__builtin_inff(), -__builtin_inff()};
    float lrow[2] = {0.f, 0.f};
    f4_t o[2][4] = {};                 // O[mf][qrow=fq*4+j][d=df*16+fr]

    auto stage = [&](int kv, int buf) {
        #pragma unroll
        for (int it = 0; it < 4; ++it) {
            const int c = tid + it * 256;
            const int cb = it * 256 + w * 64;          // wave-uniform chunk base
            const int rk = c >> 3;
            const int slk = (c & 7) ^ (rk & 7);
            const int sr = ((rk >> 2) & 3) * 32 + (rk >> 4) * 4 + (rk & 3);  // sigma
            async_copy16(&Ks[buf][cb * 8], Kb + (size_t)(kv + sr) * DKH + slk * 8);
            const int rv = c >> 4;
            const int slv = (c & 15) ^ (rv & 7);
            async_copy16(&Vs[buf][cb * 8], Vb + (size_t)rv * SS + kv + slv * 8);
        }
    };

    stage(0, 0);
    __syncthreads();
    int cur = 0;
    for (int kv = 0; kv < SS; kv += 128) {
        if (kv + 128 < SS) stage(kv + 128, cur ^ 1);

        u32 pk[2][16];  // [mf][nf*2+h]: physkeys fq*32+nf*4+{2h,2h+1}
        #pragma unroll
        for (int mf = 0; mf < 2; ++mf) {
            // S^T = K * Q^T : sa[nf][j] = S[physkey = fq*32+nf*4+j][qrow]
            f4_t sa[8] = {};
            __builtin_amdgcn_s_setprio(1);
            #pragma unroll
            for (int nf = 0; nf < 8; ++nf)
              #pragma unroll
              for (int kh = 0; kh < 2; ++kh) {
                const int row = nf * 16 + fr;
                const int dsl = (kh * 4 + fq) ^ (fr & 7);
                const bf8_t kb = *(const bf8_t*)&Ks[cur][row * 64 + dsl * 8];
                sa[nf] = MFMA32(kb, qf[mf][kh], sa[nf]);
              }
            __builtin_amdgcn_s_setprio(0);

            float x = sa[0][0];
            #pragma unroll
            for (int nf = 0; nf < 8; ++nf)
              #pragma unroll
              for (int j = 0; j < 4; ++j)
                x = fmaxf(x, sa[nf][j]);
            x = fmaxf(x, __shfl_xor(x, 16));
            x = fmaxf(x, __shfl_xor(x, 32));

            if (__any(x > mrow[mf] + 8.f)) {       // defer-max (T13)
                float mnew = fmaxf(mrow[mf], x);
                float sc = fexp2(mrow[mf] - mnew);
                lrow[mf] *= sc;
                mrow[mf] = mnew;
                float sc4[4];
                #pragma unroll
                for (int j = 0; j < 4; ++j) sc4[j] = __shfl(sc, fq * 4 + j);
                #pragma unroll
                for (int df = 0; df < 4; ++df)
                  #pragma unroll
                  for (int j = 0; j < 4; ++j)
                    o[mf][df][j] *= sc4[j];
            }

            float ps = 0.f;
            #pragma unroll
            for (int nf = 0; nf < 8; ++nf) {
                float p0 = fexp2(sa[nf][0] - mrow[mf]);
                float p1 = fexp2(sa[nf][1] - mrow[mf]);
                float p2 = fexp2(sa[nf][2] - mrow[mf]);
                float p3 = fexp2(sa[nf][3] - mrow[mf]);
                ps += (p0 + p1) + (p2 + p3);
                pk[mf][nf * 2 + 0] = cvt_pk_bf16(p0, p1);
                pk[mf][nf * 2 + 1] = cvt_pk_bf16(p2, p3);
            }
            ps += __shfl_xor(ps, 16);
            ps += __shfl_xor(ps, 32);
            lrow[mf] += ps;
        }

        // O += P V : pa[mf] = physkeys [fq*32+8t, +8); vv reused across mf
        __builtin_amdgcn_s_setprio(1);
        #pragma unroll
        for (int t = 0; t < 4; ++t) {
            union { bf8_t v; u32 u[4]; } pa0, pa1;
            #pragma unroll
            for (int i = 0; i < 4; ++i) { pa0.u[i] = pk[0][4 * t + i]; pa1.u[i] = pk[1][4 * t + i]; }
            const int sl = fq * 4 + t;
            #pragma unroll
            for (int df = 0; df < 4; ++df) {
                const int rv = df * 16 + fr;
                const int dsl = sl ^ (rv & 7);
                const bf8_t vv = *(const bf8_t*)&Vs[cur][rv * 128 + dsl * 8];
                o[0][df] = MFMA32(pa0.v, vv, o[0][df]);
                o[1][df] = MFMA32(pa1.v, vv, o[1][df]);
            }
        }
        __builtin_amdgcn_s_setprio(0);
        __syncthreads();
        cur ^= 1;
    }

    const int b = bh >> 4, h = bh & 15;
    #pragma unroll
    for (int mf = 0; mf < 2; ++mf) {
        float ml[4];
        #pragma unroll
        for (int j = 0; j < 4; ++j) ml[j] = __shfl(lrow[mf], fq * 4 + j);
        #pragma unroll
        for (int df = 0; df < 4; ++df)
          #pragma unroll
          for (int j = 0; j < 4; ++j) {
            const int s = q0 + mf * 16 + fq * 4 + j;
            const int dd = df * 16 + fr;
            float v = o[mf][df][j] / ml[j];
            ctx[((size_t)(b * SS + s)) * DM + h * DKH + dd] = f2bf(v);
          }
    }
}

// ---------------- launcher ----------------
extern "C" void kernel_launch(void* const* d_in, const int* in_sizes, int n_in,
                              void* d_out, int out_size, void* d_ws, size_t ws_size,
                              hipStream_t stream)
{
    const float* x     = (const float*)d_in[0];
    const float* W_qkv = (const float*)d_in[1];
    const float* b_qkv = (const float*)d_in[2];
    const float* W_o   = (const float*)d_in[3];
    const float* b_o   = (const float*)d_in[4];
    float* out = (float*)d_out;

    char* ws = (char*)d_ws;
    u16* xb   = (u16*)(ws);                                   // 4096x1024  (8 MB)
    u16* Wqkt = (u16*)(ws + 8388608);                         // 3072x1024  (6 MB)
    u16* Wot  = (u16*)(ws + 8388608 + 6291456);               // 1024x1024  (2 MB)
    u16* Qg   = (u16*)(ws + 16777216);                        // 32x2048x64 (8 MB)
    u16* Kg   = Qg  + 4194304;
    u16* Vg   = Kg  + 4194304;                                // V linear
    u16* Vtg  = Vg  + 4194304;                                // V transposed
    u16* ctx  = xb;                                           // alias: xb dead after k_gemm<0>

    k_prep<<<4608, 256, 0, stream>>>(x, W_qkv, W_o, xb, Wqkt, Wot);
    k_gemm<0, 128, 128><<<dim3(3 * DM / 128, MROWS / 128), 256, 0, stream>>>(
        xb, Wqkt, b_qkv, Qg, Kg, Vg, nullptr, 3 * DM, DM);
    k_vt<<<dim3(SS / 64, BB * NHEADS), 256, 0, stream>>>(Vg, Vtg);
    k_attn<<<dim3(BB * NHEADS, SS / 128), 256, 0, stream>>>(Qg, Kg, Vtg, ctx);
    k_gemm<1, 64, 64><<<dim3(DM / 64, MROWS / 64), 256, 0, stream>>>(
        ctx, Wot, b_o, nullptr, nullptr, nullptr, out, DM, DM);
}